// Round 19
// baseline (205.784 us; speedup 1.0000x reference)
//
#include <hip/hip_runtime.h>

#define T_ 512
#define K_ 128
#define L2E 1.4426950408889634f
#define LN2 0.6931471805599453f

__device__ __forceinline__ int irl(int v, int lane) {
    return __builtin_amdgcn_readlane(v, lane);
}

#if __has_builtin(__builtin_amdgcn_udot4)
#define DOT4(a, b, c) ((int)__builtin_amdgcn_udot4((unsigned)(a), (unsigned)(b), (unsigned)(c), false))
#define QMAXV 255
#elif __has_builtin(__builtin_amdgcn_sdot4)
#define DOT4(a, b, c) __builtin_amdgcn_sdot4((a), (b), (c), false)
#define QMAXV 127
#else
__device__ __forceinline__ int dot4_emu(int a, int b, int c) {
#pragma unroll
    for (int k = 0; k < 4; ++k)
        c += ((a >> (8 * k)) & 0xff) * ((b >> (8 * k)) & 0xff);
    return c;
}
#define DOT4(a, b, c) dot4_emu((a), (b), (c))
#define QMAXV 255
#endif

// wave64 max-reduce step via DPP (pure VALU). values >= 0 so 0-fill safe.
#define DPPMAX(m, ctrl)                                                     \
    m = fmaxf(m, __int_as_float(__builtin_amdgcn_update_dpp(                 \
                     0, __float_as_int(m), (ctrl), 0xf, 0xf, true)))

// quad_perm [1,0,3,2]: swap even/odd neighbor lanes
#define DPP_SWAP(x) __builtin_amdgcn_update_dpp(0, (x), 0xB1, 0xf, 0xf, true)

// 32 readlane + 64 udot4 in 8 independent chains -> vpre0, vpre1 (floats).
#define MATVEC()                                                             \
        int a0 = 0, a1 = 0, a2 = 0, a3 = 0;                                  \
        int c0 = 0, c1 = 0, c2 = 0, c3 = 0;                                  \
        _Pragma("unroll")                                                    \
        for (int d = 0; d < 32; d += 4) {                                    \
            const int u0 = irl(updw, 2 * d);                                 \
            const int u1 = irl(updw, 2 * d + 2);                             \
            const int u2 = irl(updw, 2 * d + 4);                             \
            const int u3 = irl(updw, 2 * d + 6);                             \
            a0 = DOT4(Eq0[d],     u0, a0);  c0 = DOT4(Eq1[d],     u0, c0);   \
            a1 = DOT4(Eq0[d + 1], u1, a1);  c1 = DOT4(Eq1[d + 1], u1, c1);   \
            a2 = DOT4(Eq0[d + 2], u2, a2);  c2 = DOT4(Eq1[d + 2], u2, c2);   \
            a3 = DOT4(Eq0[d + 3], u3, a3);  c3 = DOT4(Eq1[d + 3], u3, c3);   \
        }                                                                    \
        const int acc0 = (a0 + a1) + (a2 + a3);                              \
        const int acc1 = (c0 + c1) + (c2 + c3);                              \
        const float vpre0 = (float)acc0 * ehc0;                              \
        const float vpre1 = (float)acc1 * ehc1;

#define MAXCHAIN()                                                           \
        float m_ = fmaxf(vpre0, vpre1);                                      \
        DPPMAX(m_, 0x111); DPPMAX(m_, 0x112); DPPMAX(m_, 0x114);             \
        DPPMAX(m_, 0x118); DPPMAX(m_, 0x142); DPPMAX(m_, 0x143);             \
        int e_ = (int)((unsigned)irl(__float_as_int(m_), 63) >> 23) - 127;   \
        e_ = max(e_, -20);   /* encode-safety floor */

#define PACKQ()                                                              \
        qa = q0; qb = q1;                                                    \
        const int own16 = q0 | (q1 << 8);                                    \
        updw = own16 | (DPP_SWAP(own16) << 16);

#define EHCNEXT(SNEXT)                                                       \
        ehc0 = exp2f((SNEXT).x * L2E) * rE0;                                 \
        ehc1 = exp2f((SNEXT).y * L2E) * rE1;

// Adaptive-exponent body. Fast path: quantize with FROZEN eprev (no max
// chain on the critical path at all). Wave-uniform guard branch -> slow path
// (exact DPP max + requant + eprev reset) only when band [8,QMAXV] exited.
// Representation stays an exact power of 2 either way (no R17 collapse).
#define BODY(tt, SLOT, SNEXT)                                                \
    {                                                                        \
        const int tc = ((tt) + 4 < len) ? (tt) + 4 : len - 1;                \
        SLOT = hb[(size_t)tc * 64];                                          \
        MATVEC();                                                            \
        const float cnqf = __int_as_float((132 - eprev) << 23);              \
        int q0 = (int)fminf(fmaf(vpre0, cnqf, 0.5f), 3.0e5f);                \
        int q1 = (int)fminf(fmaf(vpre1, cnqf, 0.5f), 3.0e5f);                \
        int eap = eprev;                                                     \
        const int qm = max(q0, q1);                                          \
        if (__any(qm > QMAXV) || !__any(qm >= 8)) {                          \
            MAXCHAIN();                                                      \
            const float cq2 = __int_as_float((132 - e_) << 23);              \
            q0 = (int)fmaf(vpre0, cq2, 0.5f);                                \
            q1 = (int)fmaf(vpre1, cq2, 0.5f);                                \
            eprev = e_; eap = e_;                                            \
        }                                                                    \
        CMi += eap - 5;                                                      \
        q0 = min(q0, QMAXV);  q1 = min(q1, QMAXV);                           \
        PACKQ();                                                             \
        EHCNEXT(SNEXT);                                                      \
    }

// Exact-scale body for t=0 (seeds eprev).
#define BODYX(tt, SLOT, SNEXT)                                               \
    {                                                                        \
        const int tc = ((tt) + 4 < len) ? (tt) + 4 : len - 1;                \
        SLOT = hb[(size_t)tc * 64];                                          \
        MATVEC();                                                            \
        MAXCHAIN();                                                          \
        const float cq2 = __int_as_float((132 - e_) << 23);                  \
        int q0 = (int)fmaf(vpre0, cq2, 0.5f);                                \
        int q1 = (int)fmaf(vpre1, cq2, 0.5f);                                \
        eprev = e_;                                                          \
        CMi += e_ - 5;                                                       \
        q0 = min(q0, QMAXV);  q1 = min(q1, QMAXV);                           \
        PACKQ();                                                             \
        EHCNEXT(SNEXT);                                                      \
    }

// One wave per batch element. Lane l owns rows 2l, 2l+1. u8 fixed-point
// exponential-space recurrence with adaptive frozen-exponent rescale.
__global__ __launch_bounds__(64)
__attribute__((amdgpu_waves_per_eu(1, 1)))
void crf_fwd(const float* __restrict__ h,
             const float* __restrict__ trans,
             const int* __restrict__ lengths,
             float* __restrict__ out)
{
    const int b  = blockIdx.x;
    const int l  = threadIdx.x;       // 0..63
    const int r0 = 2 * l, r1 = 2 * l + 1;

    // ---- preamble pass 1: row maxima of E = exp(trans) ----
    const float4* ta = (const float4*)(trans + r0 * K_);
    const float4* tb = (const float4*)(trans + r1 * K_);
    float mx0 = 0.f, mx1 = 0.f;
#pragma unroll
    for (int q = 0; q < 32; ++q) {
        const float4 x = ta[q];
        mx0 = fmaxf(mx0, fmaxf(fmaxf(exp2f(x.x * L2E), exp2f(x.y * L2E)),
                               fmaxf(exp2f(x.z * L2E), exp2f(x.w * L2E))));
        const float4 y = tb[q];
        mx1 = fmaxf(mx1, fmaxf(fmaxf(exp2f(y.x * L2E), exp2f(y.y * L2E)),
                               fmaxf(exp2f(y.z * L2E), exp2f(y.w * L2E))));
    }
    mx0 = fmaxf(mx0, 1e-30f);
    mx1 = fmaxf(mx1, 1e-30f);
    const float sE0 = (float)QMAXV / mx0, sE1 = (float)QMAXV / mx1;
    const float rE0 = mx0 * (1.0f / (float)QMAXV);
    const float rE1 = mx1 * (1.0f / (float)QMAXV);

    // ---- preamble pass 2: quantize E rows to u8, pack 4/dword ----
    int Eq0[32], Eq1[32];
#pragma unroll
    for (int q = 0; q < 32; ++q) {
        const float4 x = ta[q];
        const int A0 = (int)(exp2f(x.x * L2E) * sE0 + 0.5f);
        const int A1 = (int)(exp2f(x.y * L2E) * sE0 + 0.5f);
        const int A2 = (int)(exp2f(x.z * L2E) * sE0 + 0.5f);
        const int A3 = (int)(exp2f(x.w * L2E) * sE0 + 0.5f);
        Eq0[q] = A0 | (A1 << 8) | (A2 << 16) | (A3 << 24);
        const float4 y = tb[q];
        const int C0 = (int)(exp2f(y.x * L2E) * sE1 + 0.5f);
        const int C1 = (int)(exp2f(y.y * L2E) * sE1 + 0.5f);
        const int C2 = (int)(exp2f(y.z * L2E) * sE1 + 0.5f);
        const int C3 = (int)(exp2f(y.w * L2E) * sE1 + 0.5f);
        Eq1[q] = C0 | (C1 << 8) | (C2 << 16) | (C3 << 24);
    }

    const int len = lengths[b];
    const float2* hb = (const float2*)(h + (size_t)b * (T_ * K_) + r0);

    // state: one-hot at START=127 -> q[127]=64, CMi=-6 (64*2^-6 = 1)
    int qa = 0, qb = (l == 63) ? 64 : 0;
    int CMi = -6;
    int eprev = 6;
    int updw;
    {
        const int own16 = qa | (qb << 8);
        updw = own16 | (DPP_SWAP(own16) << 16);
    }

    float2 s0 = hb[0];
    float2 s1 = hb[(size_t)((1 < len) ? 1 : len - 1) * 64];
    float2 s2 = hb[(size_t)((2 < len) ? 2 : len - 1) * 64];
    float2 s3 = hb[(size_t)((3 < len) ? 3 : len - 1) * 64];
    float ehc0 = exp2f(s0.x * L2E) * rE0;
    float ehc1 = exp2f(s0.y * L2E) * rE1;

    // prologue: t=0 exact (seeds eprev)
    BODYX(0, s0, s1);

    // main loop: body t refills slot t%4; SNEXT = slot (t+1)%4.
    int t = 1;
    for (; t + 3 < len; t += 4) {
        BODY(t + 0, s1, s2);
        BODY(t + 1, s2, s3);
        BODY(t + 2, s3, s0);
        BODY(t + 3, s0, s1);
    }
    if (t     < len) BODY(t,     s1, s2);
    if (t + 1 < len) BODY(t + 1, s2, s3);
    if (t + 2 < len) BODY(t + 2, s3, s0);

    // ---- out[b] = ln2 * (CMi + log2( sum_i q_i * exp(trans[END,i]) )) ----
    const float tEa = exp2f(trans[(K_ - 2) * K_ + r0] * L2E);
    const float tEb = exp2f(trans[(K_ - 2) * K_ + r1] * L2E);
    float s = (float)qa * tEa + (float)qb * tEb;
#pragma unroll
    for (int off = 32; off >= 1; off >>= 1)
        s += __shfl_xor(s, off, 64);
    if (l == 0) out[b] = ((float)CMi + log2f(s)) * LN2;
}

extern "C" void kernel_launch(void* const* d_in, const int* in_sizes, int n_in,
                              void* d_out, int out_size, void* d_ws, size_t ws_size,
                              hipStream_t stream) {
    const float* h       = (const float*)d_in[0];
    const float* trans   = (const float*)d_in[1];
    const int*   lengths = (const int*)d_in[2];
    float*       out     = (float*)d_out;
    const int B = in_sizes[2];   // 512
    crf_fwd<<<B, 64, 0, stream>>>(h, trans, lengths, out);
}